// Round 5
// baseline (134.611 us; speedup 1.0000x reference)
//
#include <hip/hip_runtime.h>

#define P_TERMS 24

typedef _Float16 f16x8 __attribute__((ext_vector_type(8)));
typedef float f32x16 __attribute__((ext_vector_type(16)));

static __device__ __forceinline__ unsigned pk2(float a, float b) {
  unsigned d;
  asm("v_cvt_pkrtz_f16_f32 %0, %1, %2" : "=v"(d) : "v"(a), "v"(b));
  return d;
}
// d.lo = a.lo + b.hi ; d.hi = a.hi + b.lo   (f16x2, swapped src1)
static __device__ __forceinline__ unsigned pkadd_sw(unsigned a, unsigned b) {
  unsigned d;
  asm("v_pk_add_f16 %0, %1, %2 op_sel:[0,1] op_sel_hi:[1,0]"
      : "=v"(d) : "v"(a), "v"(b));
  return d;
}

// ---------------- K1: c_p = A^p B (sequential, tiny), E[p][m] = C . c_p ----
__global__ __launch_bounds__(256) void s4_powers(
    const float* __restrict__ A, const float* __restrict__ B,
    const float* __restrict__ C, float* __restrict__ E) {
  __shared__ float cp[P_TERMS + 1][64];
  __shared__ float cur[64];
  const int tid = threadIdx.x;
  if (tid < 64) { cur[tid] = B[tid]; cp[0][tid] = B[tid]; }
  __syncthreads();
  const int n = tid >> 2, g = tid & 3;
  for (int p = 1; p <= P_TERMS; ++p) {
    float s = 0.f;
    const int j0 = g * 16;
#pragma unroll
    for (int j = 0; j < 16; ++j) s += A[n * 64 + j0 + j] * cur[j0 + j];
    s += __shfl_xor(s, 1);
    s += __shfl_xor(s, 2);
    __syncthreads();
    if (g == 0) { cur[n] = s; cp[p][n] = s; }
    __syncthreads();
  }
  const int m = tid;  // 0..255
#pragma unroll 1
  for (int p = 0; p <= P_TERMS; ++p) {
    float s = 0.f;
    for (int nn = 0; nn < 64; ++nn) s += C[m * 64 + nn] * cp[p][nn];
    E[p * 256 + m] = s;
  }
}

// ------- K2: W[k][m] = sum_p binom(k,p) dt^p E[p][m]; store f16 [k/8][m][8]
__global__ __launch_bounds__(512) void s4_wt(
    const float* __restrict__ E, const float* __restrict__ log_dt,
    _Float16* __restrict__ Wt8) {
  __shared__ float Em[P_TERMS + 1];
  const int m = blockIdx.x;
  const int k = threadIdx.x;  // 0..511
  if (k <= P_TERMS) Em[k] = E[k * 256 + m];
  __syncthreads();
  const float dt = __expf(log_dt[0]);
  float coef = 1.f, s = Em[0];
#pragma unroll 1
  for (int p = 1; p <= P_TERMS; ++p) {
    coef *= dt * (float)(k - p + 1) / (float)p;  // zero for p>k, stays zero
    s += coef * Em[p];
  }
  Wt8[((size_t)(k >> 3) * 256 + m) * 8 + (k & 7)] = (_Float16)s;
}

// ---------------- K3: Y = dt * (G @ W) + 2 u D --------------------------
// A = G (rows t, built from LDS quads w/ in-register reversal), B = W
// ([k/8][m][8] coalesced global, L1-shared across waves). Ping-pong
// software pipeline, 32t x 128m wave tile for occupancy.
__global__ __launch_bounds__(256, 3) void s4_main(
    const float* __restrict__ x, const _Float16* __restrict__ Wt8,
    const float* __restrict__ Dvec, const float* __restrict__ log_dt,
    float* __restrict__ out) {
  __shared__ float us_pad[1552];  // uf(g) = us_pad[g+4]; zero-padded
  __shared__ uint4 UF8[1536];     // UF8[i] = f16{uf(i..i+7)}

  const int tid = threadIdx.x;
  const int bid = blockIdx.x;
  const int mhalf = bid & 1;
  const int tq = (bid >> 1) & 3;
  const int ch = bid >> 3;
  const int b = ch >> 8;
  const int d = ch & 255;

  for (int i = tid; i < 1552; i += 256) {
    const int g = i - 516;  // u time index
    us_pad[i] = (g >= 0 && g < 512) ? x[(b * 512 + g) * 256 + d] : 0.f;
  }
  __syncthreads();
  {
    const int i0 = tid * 6;  // 256*6 = 1536 entries
    float w[14];
#pragma unroll
    for (int j = 0; j < 14; ++j) w[j] = us_pad[i0 + 4 + j];
    unsigned P[13];
#pragma unroll
    for (int j = 0; j < 13; ++j) P[j] = pk2(w[j], w[j + 1]);
#pragma unroll
    for (int e = 0; e < 6; ++e)
      UF8[i0 + e] = make_uint4(P[e], P[e + 2], P[e + 4], P[e + 6]);
  }
  __syncthreads();

  const int lane = tid & 63;
  const int wid = tid >> 6;
  const int r = lane & 31;
  const int hi = lane >> 5;
  const int tbase = tq * 128 + wid * 32;  // wave covers 32 t
  const int mb = mhalf * 128;             // wave covers 128 m
  const int t0 = tbase + r;

  f32x16 acc[4];
#pragma unroll
  for (int mi = 0; mi < 4; ++mi)
#pragma unroll
    for (int e = 0; e < 16; ++e) acc[mi][e] = 0.f;

  int i_f = 512 + t0 + hi * 8;  // fwd window start
  int i_r = 505 + t0 - hi * 8;  // rev window start
  const _Float16* wkp = Wt8 + ((size_t)(mb + r) << 3) + ((size_t)hi << 11);

  // ---- software-pipelined main loop: 2 k-steps (32 k) per iteration ----
  uint4 Fa = UF8[i_f];
  uint4 Ra = UF8[i_r];
  f16x8 wa[4];
#pragma unroll
  for (int mi = 0; mi < 4; ++mi)
    wa[mi] = *reinterpret_cast<const f16x8*>(wkp + mi * 256);

#pragma unroll 1
  for (int kk = 0; kk < 512; kk += 32) {
    // prefetch B set (k-step kk+16) — always in range
    const uint4 Fb = UF8[i_f + 16];
    const uint4 Rb = UF8[i_r - 16];
    f16x8 wb[4];
#pragma unroll
    for (int mi = 0; mi < 4; ++mi)
      wb[mi] = *reinterpret_cast<const f16x8*>(wkp + 4096 + mi * 256);

    // compute A set (k-step kk)
    {
      union { unsigned w[4]; f16x8 v; } g0;
      g0.w[0] = pkadd_sw(Fa.x, Ra.w);
      g0.w[1] = pkadd_sw(Fa.y, Ra.z);
      g0.w[2] = pkadd_sw(Fa.z, Ra.y);
      g0.w[3] = pkadd_sw(Fa.w, Ra.x);
#pragma unroll
      for (int mi = 0; mi < 4; ++mi)
        acc[mi] = __builtin_amdgcn_mfma_f32_32x32x16_f16(g0.v, wa[mi],
                                                         acc[mi], 0, 0, 0);
    }

    // prefetch A set for k-step kk+32 (clamped on final iteration; unused)
    {
      const int i_f2 = (i_f + 32 > 1535) ? 1535 : i_f + 32;
      const int i_r2 = (i_r - 32 < 0) ? 0 : i_r - 32;
      const _Float16* wk2 = (kk < 480) ? wkp + 8192 : wkp;
      Fa = UF8[i_f2];
      Ra = UF8[i_r2];
#pragma unroll
      for (int mi = 0; mi < 4; ++mi)
        wa[mi] = *reinterpret_cast<const f16x8*>(wk2 + mi * 256);
    }

    // compute B set (k-step kk+16)
    {
      union { unsigned w[4]; f16x8 v; } g1;
      g1.w[0] = pkadd_sw(Fb.x, Rb.w);
      g1.w[1] = pkadd_sw(Fb.y, Rb.z);
      g1.w[2] = pkadd_sw(Fb.z, Rb.y);
      g1.w[3] = pkadd_sw(Fb.w, Rb.x);
#pragma unroll
      for (int mi = 0; mi < 4; ++mi)
        acc[mi] = __builtin_amdgcn_mfma_f32_32x32x16_f16(g1.v, wb[mi],
                                                         acc[mi], 0, 0, 0);
    }

    i_f += 32;
    i_r -= 32;
    wkp += 8192;
  }

  const float dtv = __expf(log_dt[0]);
  const int tb2 = tbase + 4 * hi;
#pragma unroll
  for (int mi = 0; mi < 4; ++mi) {
    const int m = mb + mi * 32 + r;
    const float Dm = Dvec[m];
#pragma unroll
    for (int reg = 0; reg < 16; ++reg) {
      const int trow = tb2 + (reg & 3) + 8 * (reg >> 2);
      const float uv = us_pad[516 + trow];
      __builtin_nontemporal_store(
          dtv * acc[mi][reg] + 2.f * uv * Dm,
          &out[(((size_t)b * 512 + trow) * 256 + d) * 256 + m]);
    }
  }
}

extern "C" void kernel_launch(void* const* d_in, const int* in_sizes, int n_in,
                              void* d_out, int out_size, void* d_ws, size_t ws_size,
                              hipStream_t stream) {
  (void)in_sizes; (void)n_in; (void)out_size; (void)ws_size;
  const float* x = (const float*)d_in[0];
  const float* A = (const float*)d_in[1];
  const float* B = (const float*)d_in[2];
  const float* C = (const float*)d_in[3];
  const float* D = (const float*)d_in[4];
  const float* log_dt = (const float*)d_in[5];
  float* out = (float*)d_out;

  float* E = (float*)d_ws;                           // 25*256*4 = 25.6 KB
  _Float16* Wt8 = (_Float16*)((char*)d_ws + 32768);  // 512*256*2 = 256 KB

  s4_powers<<<1, 256, 0, stream>>>(A, B, C, E);
  s4_wt<<<256, 512, 0, stream>>>(E, log_dt, Wt8);
  s4_main<<<4096, 256, 0, stream>>>(x, Wt8, D, log_dt, out);
}

// Round 6
// 118.827 us; speedup vs baseline: 1.1328x; 1.1328x over previous
//
#include <hip/hip_runtime.h>

#define P_TERMS 24

typedef _Float16 f16x8 __attribute__((ext_vector_type(8)));
typedef float f32x16 __attribute__((ext_vector_type(16)));

static __device__ __forceinline__ unsigned pk2(float a, float b) {
  unsigned d;
  asm("v_cvt_pkrtz_f16_f32 %0, %1, %2" : "=v"(d) : "v"(a), "v"(b));
  return d;
}
// d.lo = a.lo + b.hi ; d.hi = a.hi + b.lo   (f16x2, swapped src1)
static __device__ __forceinline__ unsigned pkadd_sw(unsigned a, unsigned b) {
  unsigned d;
  asm("v_pk_add_f16 %0, %1, %2 op_sel:[0,1] op_sel_hi:[1,0]"
      : "=v"(d) : "v"(a), "v"(b));
  return d;
}

// ---------------- K1: c_p = A^p B (sequential, tiny), E[p][m] = C . c_p ----
__global__ __launch_bounds__(256) void s4_powers(
    const float* __restrict__ A, const float* __restrict__ B,
    const float* __restrict__ C, float* __restrict__ E) {
  __shared__ float cp[P_TERMS + 1][64];
  __shared__ float cur[64];
  const int tid = threadIdx.x;
  if (tid < 64) { cur[tid] = B[tid]; cp[0][tid] = B[tid]; }
  __syncthreads();
  const int n = tid >> 2, g = tid & 3;
  for (int p = 1; p <= P_TERMS; ++p) {
    float s = 0.f;
    const int j0 = g * 16;
#pragma unroll
    for (int j = 0; j < 16; ++j) s += A[n * 64 + j0 + j] * cur[j0 + j];
    s += __shfl_xor(s, 1);
    s += __shfl_xor(s, 2);
    __syncthreads();
    if (g == 0) { cur[n] = s; cp[p][n] = s; }
    __syncthreads();
  }
  const int m = tid;  // 0..255
#pragma unroll 1
  for (int p = 0; p <= P_TERMS; ++p) {
    float s = 0.f;
    for (int nn = 0; nn < 64; ++nn) s += C[m * 64 + nn] * cp[p][nn];
    E[p * 256 + m] = s;
  }
}

// ------- K2: W[k][m] = sum_p binom(k,p) dt^p E[p][m]; store f16 [k/8][m][8]
__global__ __launch_bounds__(512) void s4_wt(
    const float* __restrict__ E, const float* __restrict__ log_dt,
    _Float16* __restrict__ Wt8) {
  __shared__ float Em[P_TERMS + 1];
  const int m = blockIdx.x;
  const int k = threadIdx.x;  // 0..511
  if (k <= P_TERMS) Em[k] = E[k * 256 + m];
  __syncthreads();
  const float dt = __expf(log_dt[0]);
  float coef = 1.f, s = Em[0];
#pragma unroll 1
  for (int p = 1; p <= P_TERMS; ++p) {
    coef *= dt * (float)(k - p + 1) / (float)p;  // zero for p>k, stays zero
    s += coef * Em[p];
  }
  Wt8[((size_t)(k >> 3) * 256 + m) * 8 + (k & 7)] = (_Float16)s;
}

// ---------------- K3: Y = dt * (G @ W) + 2 u D --------------------------
// A = G (rows t, built from LDS quads w/ in-register reversal), B = W
// ([k/8][m][8] coalesced global). Double-pass over m-halves per block
// (build amortized), setprio around MFMA cluster.
__global__ __launch_bounds__(256, 2) void s4_main(
    const float* __restrict__ x, const _Float16* __restrict__ Wt8,
    const float* __restrict__ Dvec, const float* __restrict__ log_dt,
    float* __restrict__ out) {
  __shared__ float us_pad[1552];  // uf(g) = us_pad[g+4]; zero-padded
  __shared__ uint4 UF8[1536];     // UF8[i] = f16{uf(i..i+7)}

  const int tid = threadIdx.x;
  const int bid = blockIdx.x;
  const int thalf = bid & 1;
  const int ch = bid >> 1;
  const int b = ch >> 8;
  const int d = ch & 255;

  for (int i = tid; i < 1552; i += 256) {
    const int g = i - 516;  // u time index
    us_pad[i] = (g >= 0 && g < 512) ? x[(b * 512 + g) * 256 + d] : 0.f;
  }
  __syncthreads();
  {
    const int i0 = tid * 6;  // 256*6 = 1536 entries
    float w[14];
#pragma unroll
    for (int j = 0; j < 14; ++j) w[j] = us_pad[i0 + 4 + j];
    unsigned P[13];
#pragma unroll
    for (int j = 0; j < 13; ++j) P[j] = pk2(w[j], w[j + 1]);
#pragma unroll
    for (int e = 0; e < 6; ++e)
      UF8[i0 + e] = make_uint4(P[e], P[e + 2], P[e + 4], P[e + 6]);
  }
  __syncthreads();

  const int lane = tid & 63;
  const int wid = tid >> 6;
  const int r = lane & 31;
  const int hi = lane >> 5;
  const int tbase = thalf * 256 + wid * 64;  // wave covers 64 t
  const int t0 = tbase + r;
  const int if0 = 512 + t0 + hi * 8;  // fwd window start
  const int ir0 = 505 + t0 - hi * 8;  // rev window start
  const float dtv = __expf(log_dt[0]);

#pragma unroll 1
  for (int mh = 0; mh < 2; ++mh) {
    const int mb = mh << 7;  // wave covers 128 m per pass

    f32x16 acc[2][4];
#pragma unroll
    for (int ti = 0; ti < 2; ++ti)
#pragma unroll
      for (int mi = 0; mi < 4; ++mi)
#pragma unroll
        for (int e = 0; e < 16; ++e) acc[ti][mi][e] = 0.f;

    int i_f = if0;
    int i_r = ir0;
    const _Float16* wkp = Wt8 + ((size_t)(mb + r) << 3) + ((size_t)hi << 11);

    for (int kk = 0; kk < 512; kk += 16) {
      const uint4 F0 = UF8[i_f];
      const uint4 F1 = UF8[i_f + 32];
      const uint4 R0 = UF8[i_r];
      const uint4 R1 = UF8[i_r + 32];
      union { unsigned w[4]; f16x8 v; } g0, g1;
      g0.w[0] = pkadd_sw(F0.x, R0.w);
      g0.w[1] = pkadd_sw(F0.y, R0.z);
      g0.w[2] = pkadd_sw(F0.z, R0.y);
      g0.w[3] = pkadd_sw(F0.w, R0.x);
      g1.w[0] = pkadd_sw(F1.x, R1.w);
      g1.w[1] = pkadd_sw(F1.y, R1.z);
      g1.w[2] = pkadd_sw(F1.z, R1.y);
      g1.w[3] = pkadd_sw(F1.w, R1.x);

      f16x8 wf[4];
#pragma unroll
      for (int mi = 0; mi < 4; ++mi)
        wf[mi] = *reinterpret_cast<const f16x8*>(wkp + mi * 256);

      __builtin_amdgcn_s_setprio(1);
#pragma unroll
      for (int mi = 0; mi < 4; ++mi) {
        acc[0][mi] = __builtin_amdgcn_mfma_f32_32x32x16_f16(g0.v, wf[mi],
                                                            acc[0][mi], 0, 0, 0);
        acc[1][mi] = __builtin_amdgcn_mfma_f32_32x32x16_f16(g1.v, wf[mi],
                                                            acc[1][mi], 0, 0, 0);
      }
      __builtin_amdgcn_s_setprio(0);

      i_f += 16;
      i_r -= 16;
      wkp += 4096;
    }

#pragma unroll
    for (int ti = 0; ti < 2; ++ti) {
      const int tb2 = tbase + ti * 32 + 4 * hi;
#pragma unroll
      for (int mi = 0; mi < 4; ++mi) {
        const int m = mb + mi * 32 + r;
        const float Dm = Dvec[m];
#pragma unroll
        for (int reg = 0; reg < 16; ++reg) {
          const int trow = tb2 + (reg & 3) + 8 * (reg >> 2);
          const float uv = us_pad[516 + trow];
          __builtin_nontemporal_store(
              dtv * acc[ti][mi][reg] + 2.f * uv * Dm,
              &out[(((size_t)b * 512 + trow) * 256 + d) * 256 + m]);
        }
      }
    }
  }
}

extern "C" void kernel_launch(void* const* d_in, const int* in_sizes, int n_in,
                              void* d_out, int out_size, void* d_ws, size_t ws_size,
                              hipStream_t stream) {
  (void)in_sizes; (void)n_in; (void)out_size; (void)ws_size;
  const float* x = (const float*)d_in[0];
  const float* A = (const float*)d_in[1];
  const float* B = (const float*)d_in[2];
  const float* C = (const float*)d_in[3];
  const float* D = (const float*)d_in[4];
  const float* log_dt = (const float*)d_in[5];
  float* out = (float*)d_out;

  float* E = (float*)d_ws;                           // 25*256*4 = 25.6 KB
  _Float16* Wt8 = (_Float16*)((char*)d_ws + 32768);  // 512*256*2 = 256 KB

  s4_powers<<<1, 256, 0, stream>>>(A, B, C, E);
  s4_wt<<<256, 512, 0, stream>>>(E, log_dt, Wt8);
  s4_main<<<1024, 256, 0, stream>>>(x, Wt8, D, log_dt, out);
}

// Round 7
// 115.723 us; speedup vs baseline: 1.1632x; 1.0268x over previous
//
#include <hip/hip_runtime.h>

#define P_TERMS 24

typedef _Float16 f16x8 __attribute__((ext_vector_type(8)));
typedef float f32x16 __attribute__((ext_vector_type(16)));

static __device__ __forceinline__ unsigned pk2(float a, float b) {
  unsigned d;
  asm("v_cvt_pkrtz_f16_f32 %0, %1, %2" : "=v"(d) : "v"(a), "v"(b));
  return d;
}
// d.lo = a.lo + b.hi ; d.hi = a.hi + b.lo   (f16x2, swapped src1)
static __device__ __forceinline__ unsigned pkadd_sw(unsigned a, unsigned b) {
  unsigned d;
  asm("v_pk_add_f16 %0, %1, %2 op_sel:[0,1] op_sel_hi:[1,0]"
      : "=v"(d) : "v"(a), "v"(b));
  return d;
}

// ---------------- K1: c_p = A^p B (sequential, tiny), E[p][m] = C . c_p ----
__global__ __launch_bounds__(256) void s4_powers(
    const float* __restrict__ A, const float* __restrict__ B,
    const float* __restrict__ C, float* __restrict__ E) {
  __shared__ float cp[P_TERMS + 1][64];
  __shared__ float cur[64];
  const int tid = threadIdx.x;
  if (tid < 64) { cur[tid] = B[tid]; cp[0][tid] = B[tid]; }
  __syncthreads();
  const int n = tid >> 2, g = tid & 3;
  for (int p = 1; p <= P_TERMS; ++p) {
    float s = 0.f;
    const int j0 = g * 16;
#pragma unroll
    for (int j = 0; j < 16; ++j) s += A[n * 64 + j0 + j] * cur[j0 + j];
    s += __shfl_xor(s, 1);
    s += __shfl_xor(s, 2);
    __syncthreads();
    if (g == 0) { cur[n] = s; cp[p][n] = s; }
    __syncthreads();
  }
  const int m = tid;  // 0..255
#pragma unroll 1
  for (int p = 0; p <= P_TERMS; ++p) {
    float s = 0.f;
    for (int nn = 0; nn < 64; ++nn) s += C[m * 64 + nn] * cp[p][nn];
    E[p * 256 + m] = s;
  }
}

// ------- K2: W[k][m] = sum_p binom(k,p) dt^p E[p][m]; store f16 [k/8][m][8]
__global__ __launch_bounds__(512) void s4_wt(
    const float* __restrict__ E, const float* __restrict__ log_dt,
    _Float16* __restrict__ Wt8) {
  __shared__ float Em[P_TERMS + 1];
  const int m = blockIdx.x;
  const int k = threadIdx.x;  // 0..511
  if (k <= P_TERMS) Em[k] = E[k * 256 + m];
  __syncthreads();
  const float dt = __expf(log_dt[0]);
  float coef = 1.f, s = Em[0];
#pragma unroll 1
  for (int p = 1; p <= P_TERMS; ++p) {
    coef *= dt * (float)(k - p + 1) / (float)p;  // zero for p>k, stays zero
    s += coef * Em[p];
  }
  Wt8[((size_t)(k >> 3) * 256 + m) * 8 + (k & 7)] = (_Float16)s;
}

// ---------------- K3: Y = dt * (G @ W) + 2 u D --------------------------
// ti=2 x mi=2 wave tile (acc=64 VGPR -> 4 waves/SIMD). Rolling F/R window
// registers: the ti=1 windows at +32 are the ti=0 windows of 2 ksteps
// later -> 2 LDS reads per kstep instead of 4.
__global__ __launch_bounds__(256, 4) void s4_main(
    const float* __restrict__ x, const _Float16* __restrict__ Wt8,
    const float* __restrict__ Dvec, const float* __restrict__ log_dt,
    float* __restrict__ out) {
  __shared__ float us_pad[1552];  // uf(g) = us_pad[g+4]; zero-padded
  __shared__ uint4 UF8[1568];     // UF8[i] = f16{uf(i..i+7)}; [1536,1568) zero

  const int tid = threadIdx.x;
  const int bid = blockIdx.x;
  const int mh = bid & 1;
  const int tq = (bid >> 1) & 3;
  const int ch = bid >> 3;
  const int b = ch >> 8;
  const int d = ch & 255;

  for (int i = tid; i < 1552; i += 256) {
    const int g = i - 516;  // u time index
    us_pad[i] = (g >= 0 && g < 512) ? x[(b * 512 + g) * 256 + d] : 0.f;
  }
  __syncthreads();
  {
    const int i0 = tid * 6;  // 256*6 = 1536 entries
    float w[14];
#pragma unroll
    for (int j = 0; j < 14; ++j) w[j] = us_pad[i0 + 4 + j];
    unsigned P[13];
#pragma unroll
    for (int j = 0; j < 13; ++j) P[j] = pk2(w[j], w[j + 1]);
#pragma unroll
    for (int e = 0; e < 6; ++e)
      UF8[i0 + e] = make_uint4(P[e], P[e + 2], P[e + 4], P[e + 6]);
    if (tid < 32) UF8[1536 + tid] = make_uint4(0u, 0u, 0u, 0u);
  }
  __syncthreads();

  const int lane = tid & 63;
  const int wid = tid >> 6;
  const int r = lane & 31;
  const int hi = lane >> 5;
  const int wt = wid >> 1, wm = wid & 1;
  const int tbase = tq * 128 + wt * 64;  // wave covers 64 t (2 tiles)
  const int mb = mh * 128 + wm * 64;     // wave covers 64 m (2 tiles)
  const int t0 = tbase + r;

  f32x16 acc[2][2];
#pragma unroll
  for (int ti = 0; ti < 2; ++ti)
#pragma unroll
    for (int mi = 0; mi < 2; ++mi)
#pragma unroll
      for (int e = 0; e < 16; ++e) acc[ti][mi][e] = 0.f;

  const int if0 = 512 + t0 + hi * 8;  // fwd window stream f_j = UF8[if0+16j]
  const int ir0 = 505 + t0 - hi * 8;  // rev window stream r_j = UF8[ir0-16j]

  // rolling buffers: slot j%2 holds f_j / r_{j-2} at entry of step j
  uint4 FB0 = UF8[if0];       // f_0
  uint4 FB1 = UF8[if0 + 16];  // f_1
  uint4 RB0 = UF8[ir0 + 32];  // r_{-2}
  uint4 RB1 = UF8[ir0 + 16];  // r_{-1}

  const _Float16* wkp = Wt8 + ((size_t)(mb + r) << 3) + ((size_t)hi << 11);
  int i_f = if0 + 32;
  int i_r = ir0;

#pragma unroll 1
  for (int kk = 0; kk < 512; kk += 32) {
    // ---- step A (even j): uses FB0 (f_j), RB0 (r_{j-2}) ----
    {
      const uint4 Fc = UF8[i_f];      // f_{j+2}
      const uint4 Rc = UF8[i_r];      // r_j
      f16x8 wf0 = *reinterpret_cast<const f16x8*>(wkp);
      f16x8 wf1 = *reinterpret_cast<const f16x8*>(wkp + 256);
      union { unsigned w[4]; f16x8 v; } g0, g1;
      g0.w[0] = pkadd_sw(FB0.x, Rc.w);
      g0.w[1] = pkadd_sw(FB0.y, Rc.z);
      g0.w[2] = pkadd_sw(FB0.z, Rc.y);
      g0.w[3] = pkadd_sw(FB0.w, Rc.x);
      g1.w[0] = pkadd_sw(Fc.x, RB0.w);
      g1.w[1] = pkadd_sw(Fc.y, RB0.z);
      g1.w[2] = pkadd_sw(Fc.z, RB0.y);
      g1.w[3] = pkadd_sw(Fc.w, RB0.x);
      __builtin_amdgcn_s_setprio(1);
      acc[0][0] = __builtin_amdgcn_mfma_f32_32x32x16_f16(g0.v, wf0, acc[0][0], 0, 0, 0);
      acc[0][1] = __builtin_amdgcn_mfma_f32_32x32x16_f16(g0.v, wf1, acc[0][1], 0, 0, 0);
      acc[1][0] = __builtin_amdgcn_mfma_f32_32x32x16_f16(g1.v, wf0, acc[1][0], 0, 0, 0);
      acc[1][1] = __builtin_amdgcn_mfma_f32_32x32x16_f16(g1.v, wf1, acc[1][1], 0, 0, 0);
      __builtin_amdgcn_s_setprio(0);
      FB0 = Fc;
      RB0 = Rc;
    }
    // ---- step B (odd j): uses FB1, RB1 ----
    {
      const uint4 Fc = UF8[i_f + 16];
      const uint4 Rc = UF8[i_r - 16];
      f16x8 wf0 = *reinterpret_cast<const f16x8*>(wkp + 4096);
      f16x8 wf1 = *reinterpret_cast<const f16x8*>(wkp + 4096 + 256);
      union { unsigned w[4]; f16x8 v; } g0, g1;
      g0.w[0] = pkadd_sw(FB1.x, Rc.w);
      g0.w[1] = pkadd_sw(FB1.y, Rc.z);
      g0.w[2] = pkadd_sw(FB1.z, Rc.y);
      g0.w[3] = pkadd_sw(FB1.w, Rc.x);
      g1.w[0] = pkadd_sw(Fc.x, RB1.w);
      g1.w[1] = pkadd_sw(Fc.y, RB1.z);
      g1.w[2] = pkadd_sw(Fc.z, RB1.y);
      g1.w[3] = pkadd_sw(Fc.w, RB1.x);
      __builtin_amdgcn_s_setprio(1);
      acc[0][0] = __builtin_amdgcn_mfma_f32_32x32x16_f16(g0.v, wf0, acc[0][0], 0, 0, 0);
      acc[0][1] = __builtin_amdgcn_mfma_f32_32x32x16_f16(g0.v, wf1, acc[0][1], 0, 0, 0);
      acc[1][0] = __builtin_amdgcn_mfma_f32_32x32x16_f16(g1.v, wf0, acc[1][0], 0, 0, 0);
      acc[1][1] = __builtin_amdgcn_mfma_f32_32x32x16_f16(g1.v, wf1, acc[1][1], 0, 0, 0);
      __builtin_amdgcn_s_setprio(0);
      FB1 = Fc;
      RB1 = Rc;
    }
    i_f += 32;
    i_r -= 32;
    wkp += 8192;
  }

  const float dtv = __expf(log_dt[0]);
#pragma unroll
  for (int ti = 0; ti < 2; ++ti) {
    const int tb2 = tbase + ti * 32 + 4 * hi;
#pragma unroll
    for (int mi = 0; mi < 2; ++mi) {
      const int m = mb + mi * 32 + r;
      const float Dm = Dvec[m];
#pragma unroll
      for (int reg = 0; reg < 16; ++reg) {
        const int trow = tb2 + (reg & 3) + 8 * (reg >> 2);
        const float uv = us_pad[516 + trow];
        __builtin_nontemporal_store(
            dtv * acc[ti][mi][reg] + 2.f * uv * Dm,
            &out[(((size_t)b * 512 + trow) * 256 + d) * 256 + m]);
      }
    }
  }
}

extern "C" void kernel_launch(void* const* d_in, const int* in_sizes, int n_in,
                              void* d_out, int out_size, void* d_ws, size_t ws_size,
                              hipStream_t stream) {
  (void)in_sizes; (void)n_in; (void)out_size; (void)ws_size;
  const float* x = (const float*)d_in[0];
  const float* A = (const float*)d_in[1];
  const float* B = (const float*)d_in[2];
  const float* C = (const float*)d_in[3];
  const float* D = (const float*)d_in[4];
  const float* log_dt = (const float*)d_in[5];
  float* out = (float*)d_out;

  float* E = (float*)d_ws;                           // 25*256*4 = 25.6 KB
  _Float16* Wt8 = (_Float16*)((char*)d_ws + 32768);  // 512*256*2 = 256 KB

  s4_powers<<<1, 256, 0, stream>>>(A, B, C, E);
  s4_wt<<<256, 512, 0, stream>>>(E, log_dt, Wt8);
  s4_main<<<4096, 256, 0, stream>>>(x, Wt8, D, log_dt, out);
}

// Round 8
// 114.704 us; speedup vs baseline: 1.1736x; 1.0089x over previous
//
#include <hip/hip_runtime.h>

#define P_TERMS 24

typedef _Float16 f16x8 __attribute__((ext_vector_type(8)));
typedef float f32x16 __attribute__((ext_vector_type(16)));

static __device__ __forceinline__ unsigned pk2(float a, float b) {
  unsigned d;
  asm("v_cvt_pkrtz_f16_f32 %0, %1, %2" : "=v"(d) : "v"(a), "v"(b));
  return d;
}
// d.lo = a.lo + b.hi ; d.hi = a.hi + b.lo   (f16x2, swapped src1)
static __device__ __forceinline__ unsigned pkadd_sw(unsigned a, unsigned b) {
  unsigned d;
  asm("v_pk_add_f16 %0, %1, %2 op_sel:[0,1] op_sel_hi:[1,0]"
      : "=v"(d) : "v"(a), "v"(b));
  return d;
}

// ---------------- K1: c_p = A^p B (sequential, tiny), E[p][m] = C . c_p ----
__global__ __launch_bounds__(256) void s4_powers(
    const float* __restrict__ A, const float* __restrict__ B,
    const float* __restrict__ C, float* __restrict__ E) {
  __shared__ float cp[P_TERMS + 1][64];
  __shared__ float cur[64];
  const int tid = threadIdx.x;
  if (tid < 64) { cur[tid] = B[tid]; cp[0][tid] = B[tid]; }
  __syncthreads();
  const int n = tid >> 2, g = tid & 3;
  for (int p = 1; p <= P_TERMS; ++p) {
    float s = 0.f;
    const int j0 = g * 16;
#pragma unroll
    for (int j = 0; j < 16; ++j) s += A[n * 64 + j0 + j] * cur[j0 + j];
    s += __shfl_xor(s, 1);
    s += __shfl_xor(s, 2);
    __syncthreads();
    if (g == 0) { cur[n] = s; cp[p][n] = s; }
    __syncthreads();
  }
  const int m = tid;  // 0..255
#pragma unroll 1
  for (int p = 0; p <= P_TERMS; ++p) {
    float s = 0.f;
    for (int nn = 0; nn < 64; ++nn) s += C[m * 64 + nn] * cp[p][nn];
    E[p * 256 + m] = s;
  }
}

// ------- K2: W[k][m] = sum_p binom(k,p) dt^p E[p][m]; store f16 [k/8][m][8]
__global__ __launch_bounds__(512) void s4_wt(
    const float* __restrict__ E, const float* __restrict__ log_dt,
    _Float16* __restrict__ Wt8) {
  __shared__ float Em[P_TERMS + 1];
  const int m = blockIdx.x;
  const int k = threadIdx.x;  // 0..511
  if (k <= P_TERMS) Em[k] = E[k * 256 + m];
  __syncthreads();
  const float dt = __expf(log_dt[0]);
  float coef = 1.f, s = Em[0];
#pragma unroll 1
  for (int p = 1; p <= P_TERMS; ++p) {
    coef *= dt * (float)(k - p + 1) / (float)p;  // zero for p>k, stays zero
    s += coef * Em[p];
  }
  Wt8[((size_t)(k >> 3) * 256 + m) * 8 + (k & 7)] = (_Float16)s;
}

// ---------------- K3: Y = dt * (G @ W) + 2 u D --------------------------
// ti=2 x mi=2 wave tile. Fully-unrolled 32-kstep loop with 4-deep F/R LDS
// rings and 2-deep W ring: every load lands >=2 ksteps before first use.
__global__ __launch_bounds__(256, 4) void s4_main(
    const float* __restrict__ x, const _Float16* __restrict__ Wt8,
    const float* __restrict__ Dvec, const float* __restrict__ log_dt,
    float* __restrict__ out) {
  __shared__ float us_pad[1552];  // uf(g) = us_pad[g+4]; zero-padded
  __shared__ uint4 UF8[1536];     // UF8[i] = f16{uf(i..i+7)}

  const int tid = threadIdx.x;
  const int bid = blockIdx.x;
  const int mh = bid & 1;
  const int tq = (bid >> 1) & 3;
  const int ch = bid >> 3;
  const int b = ch >> 8;
  const int d = ch & 255;

  for (int i = tid; i < 1552; i += 256) {
    const int g = i - 516;  // u time index
    us_pad[i] = (g >= 0 && g < 512) ? x[(b * 512 + g) * 256 + d] : 0.f;
  }
  __syncthreads();
  {
    const int i0 = tid * 6;  // 256*6 = 1536 entries
    float w[14];
#pragma unroll
    for (int j = 0; j < 14; ++j) w[j] = us_pad[i0 + 4 + j];
    unsigned P[13];
#pragma unroll
    for (int j = 0; j < 13; ++j) P[j] = pk2(w[j], w[j + 1]);
#pragma unroll
    for (int e = 0; e < 6; ++e)
      UF8[i0 + e] = make_uint4(P[e], P[e + 2], P[e + 4], P[e + 6]);
  }
  __syncthreads();

  const int lane = tid & 63;
  const int wid = tid >> 6;
  const int r = lane & 31;
  const int hi = lane >> 5;
  const int wt = wid >> 1, wm = wid & 1;
  const int tbase = tq * 128 + wt * 64;  // wave covers 64 t (2 tiles)
  const int mb = mh * 128 + wm * 64;     // wave covers 64 m (2 tiles)
  const int t0 = tbase + r;

  f32x16 acc[2][2];
#pragma unroll
  for (int ti = 0; ti < 2; ++ti)
#pragma unroll
    for (int mi = 0; mi < 2; ++mi)
#pragma unroll
      for (int e = 0; e < 16; ++e) acc[ti][mi][e] = 0.f;

  const int if0 = 512 + t0 + hi * 8;  // F(j) = UF8[if0 + 16j]
  const int ir0 = 505 + t0 - hi * 8;  // R(j) = UF8[ir0 - 16j]
  const _Float16* wkp = Wt8 + ((size_t)(mb + r) << 3) + ((size_t)hi << 11);

  // prologue: rings hold F(0..3); R slots j&3 -> {R(0),R(1),R(-2),R(-1)}
  uint4 Fb[4], Rb[4];
  f16x8 Wb[2][2];
  Fb[0] = UF8[if0];
  Fb[1] = UF8[if0 + 16];
  Fb[2] = UF8[if0 + 32];
  Fb[3] = UF8[if0 + 48];
  Rb[0] = UF8[ir0];
  Rb[1] = UF8[ir0 - 16];
  Rb[2] = UF8[ir0 + 32];
  Rb[3] = UF8[ir0 + 16];
  Wb[0][0] = *reinterpret_cast<const f16x8*>(wkp);
  Wb[0][1] = *reinterpret_cast<const f16x8*>(wkp + 256);
  Wb[1][0] = *reinterpret_cast<const f16x8*>(wkp + 4096);
  Wb[1][1] = *reinterpret_cast<const f16x8*>(wkp + 4096 + 256);

#pragma unroll
  for (int j = 0; j < 32; ++j) {
    const int p = j & 3;
    const int q = (j + 2) & 3;
    const int w = j & 1;
    // tile0: F(j)+R(j); tile1: F(j+2)+R(j-2) (both in slot q)
    union { unsigned w[4]; f16x8 v; } g0, g1;
    g0.w[0] = pkadd_sw(Fb[p].x, Rb[p].w);
    g0.w[1] = pkadd_sw(Fb[p].y, Rb[p].z);
    g0.w[2] = pkadd_sw(Fb[p].z, Rb[p].y);
    g0.w[3] = pkadd_sw(Fb[p].w, Rb[p].x);
    g1.w[0] = pkadd_sw(Fb[q].x, Rb[q].w);
    g1.w[1] = pkadd_sw(Fb[q].y, Rb[q].z);
    g1.w[2] = pkadd_sw(Fb[q].z, Rb[q].y);
    g1.w[3] = pkadd_sw(Fb[q].w, Rb[q].x);

    __builtin_amdgcn_s_setprio(1);
    acc[0][0] = __builtin_amdgcn_mfma_f32_32x32x16_f16(g0.v, Wb[w][0], acc[0][0], 0, 0, 0);
    acc[0][1] = __builtin_amdgcn_mfma_f32_32x32x16_f16(g0.v, Wb[w][1], acc[0][1], 0, 0, 0);
    acc[1][0] = __builtin_amdgcn_mfma_f32_32x32x16_f16(g1.v, Wb[w][0], acc[1][0], 0, 0, 0);
    acc[1][1] = __builtin_amdgcn_mfma_f32_32x32x16_f16(g1.v, Wb[w][1], acc[1][1], 0, 0, 0);
    __builtin_amdgcn_s_setprio(0);

    if (j < 30) {
      Fb[p] = UF8[if0 + 16 * (j + 4)];      // F(j+4), max F(33) idx<=1527
      Rb[q] = UF8[ir0 - 16 * (j + 2)];      // R(j+2), min idx>=1
      const _Float16* wn = wkp + (size_t)(j + 2) * 4096;  // W(j+2)<=W(31)
      Wb[w][0] = *reinterpret_cast<const f16x8*>(wn);
      Wb[w][1] = *reinterpret_cast<const f16x8*>(wn + 256);
    }
  }

  const float dtv = __expf(log_dt[0]);
#pragma unroll
  for (int ti = 0; ti < 2; ++ti) {
    const int tb2 = tbase + ti * 32 + 4 * hi;
#pragma unroll
    for (int mi = 0; mi < 2; ++mi) {
      const int m = mb + mi * 32 + r;
      const float Dm = Dvec[m];
#pragma unroll
      for (int reg = 0; reg < 16; ++reg) {
        const int trow = tb2 + (reg & 3) + 8 * (reg >> 2);
        const float uv = us_pad[516 + trow];
        out[(((size_t)b * 512 + trow) * 256 + d) * 256 + m] =
            dtv * acc[ti][mi][reg] + 2.f * uv * Dm;
      }
    }
  }
}

extern "C" void kernel_launch(void* const* d_in, const int* in_sizes, int n_in,
                              void* d_out, int out_size, void* d_ws, size_t ws_size,
                              hipStream_t stream) {
  (void)in_sizes; (void)n_in; (void)out_size; (void)ws_size;
  const float* x = (const float*)d_in[0];
  const float* A = (const float*)d_in[1];
  const float* B = (const float*)d_in[2];
  const float* C = (const float*)d_in[3];
  const float* D = (const float*)d_in[4];
  const float* log_dt = (const float*)d_in[5];
  float* out = (float*)d_out;

  float* E = (float*)d_ws;                           // 25*256*4 = 25.6 KB
  _Float16* Wt8 = (_Float16*)((char*)d_ws + 32768);  // 512*256*2 = 256 KB

  s4_powers<<<1, 256, 0, stream>>>(A, B, C, E);
  s4_wt<<<256, 512, 0, stream>>>(E, log_dt, Wt8);
  s4_main<<<4096, 256, 0, stream>>>(x, Wt8, D, log_dt, out);
}

// Round 9
// 86.050 us; speedup vs baseline: 1.5643x; 1.3330x over previous
//
#include <hip/hip_runtime.h>

#define P_TERMS 24

typedef _Float16 f16x8 __attribute__((ext_vector_type(8)));
typedef float f32x16 __attribute__((ext_vector_type(16)));

static __device__ __forceinline__ unsigned pk2(float a, float b) {
  unsigned d;
  asm("v_cvt_pkrtz_f16_f32 %0, %1, %2" : "=v"(d) : "v"(a), "v"(b));
  return d;
}
// d.lo = a.lo + b.hi ; d.hi = a.hi + b.lo   (f16x2, swapped src1)
static __device__ __forceinline__ unsigned pkadd_sw(unsigned a, unsigned b) {
  unsigned d;
  asm("v_pk_add_f16 %0, %1, %2 op_sel:[0,1] op_sel_hi:[1,0]"
      : "=v"(d) : "v"(a), "v"(b));
  return d;
}

// ---------------- K1: cp[p] = A^p B (sequential, tiny) -> Fp[p][n] --------
__global__ __launch_bounds__(256) void s4_powers(
    const float* __restrict__ A, const float* __restrict__ B,
    float* __restrict__ Fp) {
  __shared__ float cp[P_TERMS + 1][64];
  __shared__ float cur[64];
  const int tid = threadIdx.x;
  if (tid < 64) { cur[tid] = B[tid]; cp[0][tid] = B[tid]; }
  __syncthreads();
  const int n = tid >> 2, g = tid & 3;
  for (int p = 1; p <= P_TERMS; ++p) {
    float s = 0.f;
    const int j0 = g * 16;
#pragma unroll
    for (int j = 0; j < 16; ++j) s += A[n * 64 + j0 + j] * cur[j0 + j];
    s += __shfl_xor(s, 1);
    s += __shfl_xor(s, 2);
    __syncthreads();
    if (g == 0) { cur[n] = s; cp[p][n] = s; }
    __syncthreads();
  }
  for (int i = tid; i < (P_TERMS + 1) * 64; i += 256)
    Fp[i] = cp[i >> 6][i & 63];
}

// ------- K2h: H[n,k] = sum_p binom(k,p) dt^p cp[p][n]; store f16 [k/8][n][8]
__global__ __launch_bounds__(512) void s4_h8(
    const float* __restrict__ Fp, const float* __restrict__ log_dt,
    _Float16* __restrict__ H8) {
  __shared__ float Fm[P_TERMS + 1];
  const int n = blockIdx.x;
  const int k = threadIdx.x;  // 0..511
  if (k <= P_TERMS) Fm[k] = Fp[k * 64 + n];
  __syncthreads();
  const float dt = __expf(log_dt[0]);
  float coef = 1.f, s = Fm[0];
#pragma unroll 1
  for (int p = 1; p <= P_TERMS; ++p) {
    coef *= dt * (float)(k - p + 1) / (float)p;  // zero for p>k, stays zero
    s += coef * Fm[p];
  }
  H8[((size_t)(k >> 3) * 64 + n) * 8 + (k & 7)] = (_Float16)s;
}

// ------- K2c: Ct8[n/8][m][8] = C[m][n] (f16) ------------------------------
__global__ __launch_bounds__(256) void s4_ct(
    const float* __restrict__ C, _Float16* __restrict__ Ct8) {
  const int n = blockIdx.x;   // 0..63
  const int m = threadIdx.x;  // 0..255
  Ct8[((size_t)(n >> 3) * 256 + m) * 8 + (n & 7)] = (_Float16)C[m * 64 + n];
}

// ---------------- K3: rank-64 factored  Y = dt*(G@H^T)@C^T + 2 u D --------
// Stage 1: Z^T[n,t] = mfma(A=H, B=G) per 64t wave strip (k=512 loop).
// Z bounced via padded LDS (wave-private rows, no barrier) into stage-2
// A-frag layout. Stage 2: Y[t,m] = mfma(A=Z, B=C^T) with k=n=64.
__global__ __launch_bounds__(256, 2) void s4_main(
    const float* __restrict__ x, const _Float16* __restrict__ H8,
    const _Float16* __restrict__ Ct8, const float* __restrict__ Dvec,
    const float* __restrict__ log_dt, float* __restrict__ out) {
  __shared__ float us[512];       // u for this channel
  __shared__ uint4 UF8[1536];     // UF8[i] = f16{uf(i..i+7)}, uf(g)=u[g-512] guarded
  __shared__ unsigned Zl[256][34];  // Z f16-pairs, padded rows (136B)

  const int tid = threadIdx.x;
  const int bid = blockIdx.x;
  const int th = bid & 1;   // t half
  const int ch = bid >> 1;
  const int b = ch >> 8;
  const int d = ch & 255;

  for (int i = tid; i < 512; i += 256) us[i] = x[(b * 512 + i) * 256 + d];
  __syncthreads();
  {
    const int i0 = tid * 6;  // 256*6 = 1536 windows
    float w[14];
#pragma unroll
    for (int j = 0; j < 14; ++j) {
      const int g = i0 + j - 512;
      const float v = us[g & 511];
      w[j] = (g >= 0 && g < 512) ? v : 0.f;
    }
    unsigned P[13];
#pragma unroll
    for (int j = 0; j < 13; ++j) P[j] = pk2(w[j], w[j + 1]);
#pragma unroll
    for (int e = 0; e < 6; ++e)
      UF8[i0 + e] = make_uint4(P[e], P[e + 2], P[e + 4], P[e + 6]);
  }
  __syncthreads();

  const int lane = tid & 63;
  const int wid = tid >> 6;
  const int r = lane & 31;
  const int hi = lane >> 5;
  const int tw = wid * 64;        // local strip base (0..192)
  const int tg0 = th * 256 + tw;  // global strip base
  const int tl0 = tw + r;         // local t of tile0 row r

  // ---------------- stage 1: Z^T = H @ G ----------------
  f32x16 acc[2][2];  // [ti][ni]
#pragma unroll
  for (int ti = 0; ti < 2; ++ti)
#pragma unroll
    for (int ni = 0; ni < 2; ++ni)
#pragma unroll
      for (int e = 0; e < 16; ++e) acc[ti][ni][e] = 0.f;

  int ifj = 512 + tg0 + r + hi * 8;  // F(j) tile0; tile1 at +32
  int irj = 505 + tg0 + r - hi * 8;  // R(j) tile0; tile1 at +32
  const _Float16* hp = H8 + hi * 512 + r * 8;

#pragma unroll 1
  for (int j = 0; j < 32; ++j) {
    const uint4 F0 = UF8[ifj];
    const uint4 R0 = UF8[irj];
    const uint4 F1 = UF8[ifj + 32];
    const uint4 R1 = UF8[irj + 32];
    const f16x8 h0 = *reinterpret_cast<const f16x8*>(hp);
    const f16x8 h1 = *reinterpret_cast<const f16x8*>(hp + 256);
    union { unsigned w[4]; f16x8 v; } g0, g1;
    g0.w[0] = pkadd_sw(F0.x, R0.w);
    g0.w[1] = pkadd_sw(F0.y, R0.z);
    g0.w[2] = pkadd_sw(F0.z, R0.y);
    g0.w[3] = pkadd_sw(F0.w, R0.x);
    g1.w[0] = pkadd_sw(F1.x, R1.w);
    g1.w[1] = pkadd_sw(F1.y, R1.z);
    g1.w[2] = pkadd_sw(F1.z, R1.y);
    g1.w[3] = pkadd_sw(F1.w, R1.x);
    __builtin_amdgcn_s_setprio(1);
    acc[0][0] = __builtin_amdgcn_mfma_f32_32x32x16_f16(h0, g0.v, acc[0][0], 0, 0, 0);
    acc[0][1] = __builtin_amdgcn_mfma_f32_32x32x16_f16(h1, g0.v, acc[0][1], 0, 0, 0);
    acc[1][0] = __builtin_amdgcn_mfma_f32_32x32x16_f16(h0, g1.v, acc[1][0], 0, 0, 0);
    acc[1][1] = __builtin_amdgcn_mfma_f32_32x32x16_f16(h1, g1.v, acc[1][1], 0, 0, 0);
    __builtin_amdgcn_s_setprio(0);
    ifj += 16;
    irj -= 16;
    hp += 1024;
  }

  // Z -> LDS (f16 pairs). D-layout: col t = lane&31, row n = (reg&3)+8q+4hi+32ni
#pragma unroll
  for (int ti = 0; ti < 2; ++ti) {
    const int t = tl0 + ti * 32;
#pragma unroll
    for (int ni = 0; ni < 2; ++ni) {
#pragma unroll
      for (int q = 0; q < 4; ++q) {
        uint2 v;
        v.x = pk2(acc[ti][ni][4 * q + 0], acc[ti][ni][4 * q + 1]);
        v.y = pk2(acc[ti][ni][4 * q + 2], acc[ti][ni][4 * q + 3]);
        *reinterpret_cast<uint2*>(&Zl[t][ni * 16 + q * 4 + 2 * hi]) = v;
      }
    }
  }
  // wave reads only its own rows below; per-wave lgkm ordering suffices.

  // ---------------- stage 2: Y = Z @ C^T + 2uD ----------------
  const float dtv = __expf(log_dt[0]);
#pragma unroll 1
  for (int mp = 0; mp < 4; ++mp) {
    const int mb2 = mp * 64;
    f32x16 y[2][2];  // [ti][mi]
#pragma unroll
    for (int ti = 0; ti < 2; ++ti)
#pragma unroll
      for (int mi = 0; mi < 2; ++mi)
#pragma unroll
        for (int e = 0; e < 16; ++e) y[ti][mi][e] = 0.f;

#pragma unroll
    for (int ks = 0; ks < 4; ++ks) {
      const int c0 = 8 * ks + 4 * hi;
      union { uint2 u[2]; f16x8 v; } z0, z1;
      z0.u[0] = *reinterpret_cast<const uint2*>(&Zl[tl0][c0]);
      z0.u[1] = *reinterpret_cast<const uint2*>(&Zl[tl0][c0 + 2]);
      z1.u[0] = *reinterpret_cast<const uint2*>(&Zl[tl0 + 32][c0]);
      z1.u[1] = *reinterpret_cast<const uint2*>(&Zl[tl0 + 32][c0 + 2]);
      const _Float16* cb = Ct8 + ((size_t)(2 * ks + hi) * 256 + mb2 + r) * 8;
      const f16x8 c0f = *reinterpret_cast<const f16x8*>(cb);
      const f16x8 c1f = *reinterpret_cast<const f16x8*>(cb + 256);
      __builtin_amdgcn_s_setprio(1);
      y[0][0] = __builtin_amdgcn_mfma_f32_32x32x16_f16(z0.v, c0f, y[0][0], 0, 0, 0);
      y[0][1] = __builtin_amdgcn_mfma_f32_32x32x16_f16(z0.v, c1f, y[0][1], 0, 0, 0);
      y[1][0] = __builtin_amdgcn_mfma_f32_32x32x16_f16(z1.v, c0f, y[1][0], 0, 0, 0);
      y[1][1] = __builtin_amdgcn_mfma_f32_32x32x16_f16(z1.v, c1f, y[1][1], 0, 0, 0);
      __builtin_amdgcn_s_setprio(0);
    }

#pragma unroll
    for (int ti = 0; ti < 2; ++ti) {
      const int tb2 = th * 256 + tw + ti * 32 + 4 * hi;
#pragma unroll
      for (int mi = 0; mi < 2; ++mi) {
        const int m = mb2 + mi * 32 + r;
        const float Dm = Dvec[m];
#pragma unroll
        for (int reg = 0; reg < 16; ++reg) {
          const int trow = tb2 + (reg & 3) + 8 * (reg >> 2);
          const float uv = us[trow];
          out[(((size_t)b * 512 + trow) * 256 + d) * 256 + m] =
              dtv * y[ti][mi][reg] + 2.f * uv * Dm;
        }
      }
    }
  }
}

extern "C" void kernel_launch(void* const* d_in, const int* in_sizes, int n_in,
                              void* d_out, int out_size, void* d_ws, size_t ws_size,
                              hipStream_t stream) {
  (void)in_sizes; (void)n_in; (void)out_size; (void)ws_size;
  const float* x = (const float*)d_in[0];
  const float* A = (const float*)d_in[1];
  const float* B = (const float*)d_in[2];
  const float* C = (const float*)d_in[3];
  const float* D = (const float*)d_in[4];
  const float* log_dt = (const float*)d_in[5];
  float* out = (float*)d_out;

  float* Fp = (float*)d_ws;                            // 25*64*4   = 6.4 KB
  _Float16* H8 = (_Float16*)((char*)d_ws + 8192);      // 512*64*2  = 64 KB
  _Float16* Ct8 = (_Float16*)((char*)d_ws + 73728);    // 64*256*2  = 32 KB

  s4_powers<<<1, 256, 0, stream>>>(A, B, Fp);
  s4_h8<<<64, 512, 0, stream>>>(Fp, log_dt, H8);
  s4_ct<<<64, 256, 0, stream>>>(C, Ct8);
  s4_main<<<1024, 256, 0, stream>>>(x, H8, Ct8, D, log_dt, out);
}